// Round 11
// baseline (184.982 us; speedup 1.0000x reference)
//
#include <hip/hip_runtime.h>

typedef __bf16 bf16;
typedef __bf16 bf16x4 __attribute__((ext_vector_type(4)));
typedef __bf16 bf16x8 __attribute__((ext_vector_type(8)));
typedef float f32x4 __attribute__((ext_vector_type(4)));

#define T_LEN   4096
#define D_MODEL 1024
#define QKV_LD  1536
#define VT_LD   4128   // 4096 + 32 pad: last tile's PV chunk over-reads into pad (x0 P)
#define WINDOW  256

// async global->LDS, 16 B per lane; data lands at readfirstlane(l) + lane*16
__device__ __forceinline__ void gload_lds16(const bf16* g, bf16* l) {
    __builtin_amdgcn_global_load_lds((const __attribute__((address_space(1))) void*)g,
                                     (__attribute__((address_space(3))) void*)l, 16, 0, 0);
}

// ---------------- fused prep: x->bf16, Wq|Wk|Wv transpose, Wo transpose -----
// grid sections: [0,2048) cvt, [2048,3584) wqkv, [3584,4608) wo

__global__ __launch_bounds__(256) void prep_fused(
    const float* __restrict__ x,
    const float* __restrict__ Wq, const float* __restrict__ Wk,
    const float* __restrict__ Wv, const float* __restrict__ Wo,
    bf16* __restrict__ xb, bf16* __restrict__ WtQKV, bf16* __restrict__ WtO)
{
    __shared__ float t[32][33];
    const int blk = blockIdx.x;
    if (blk < 2048) {                       // ---- x (f32) -> xb (bf16)
        int i = (blk * 256 + threadIdx.x) * 8;
        float4 a = *(const float4*)(x + i);
        float4 b = *(const float4*)(x + i + 4);
        bf16x8 o;
        o[0] = (bf16)a.x; o[1] = (bf16)a.y; o[2] = (bf16)a.z; o[3] = (bf16)a.w;
        o[4] = (bf16)b.x; o[5] = (bf16)b.y; o[6] = (bf16)b.z; o[7] = (bf16)b.w;
        *(bf16x8*)(xb + i) = o;
        return;
    }
    const float* W; bf16* Wt; int n0, k0, Ns, nofs;
    if (blk < 3584) {                       // ---- Wq|Wk|Wv -> WtQKV (1536x1024)
        int b = blk - 2048;
        n0 = (b % 48) * 32; k0 = (b / 48) * 32;
        if (n0 < 1024)      { W = Wq; Ns = 1024; nofs = 0; }
        else if (n0 < 1280) { W = Wk; Ns = 256;  nofs = 1024; }
        else                { W = Wv; Ns = 256;  nofs = 1280; }
        Wt = WtQKV;
    } else {                                // ---- Wo -> WtO (1024x1024)
        int b = blk - 3584;
        n0 = (b % 32) * 32; k0 = (b / 32) * 32;
        W = Wo; Ns = 1024; nofs = 0; Wt = WtO;
    }
    int tx = threadIdx.x & 31, ty = threadIdx.x >> 5;
#pragma unroll
    for (int it = 0; it < 4; ++it)
        t[ty + it * 8][tx] = W[(size_t)(k0 + ty + it * 8) * Ns + (n0 - nofs) + tx];
    __syncthreads();
#pragma unroll
    for (int it = 0; it < 4; ++it)
        Wt[(size_t)(n0 + ty + it * 8) * 1024 + k0 + tx] = (bf16)t[tx][ty + it * 8];
}

// ---------------- GEMM: C(MxN) = A(MxK)*Bt(NxK)^T + bias ----------------
// R9 config + 4-BUFFER pipeline (one extra iteration of latency slack,
// ~330 cyc, covering L2-hit latency ~200 cyc with margin — m126/m135).
// 128 threads = 2 waves; block tile 64x64, wave tile 64x32 (acc 4x2).
// LDS 4 x (4KB A + 4KB B) = 32 KB -> 5 blocks/CU. Raw s_barrier + partial
// vmcnt ladder: steady-state 12 loads in flight, wait vmcnt(8) (own 4
// oldest = current buffer landed); tail iters vmcnt(4)/vmcnt(0).
// XCD swizzle: blk&7 = XCD, bands pinned per XCD (A-band L2-resident).
// QKV_BIAS: col-blocks n0>=1280 are V -> written transposed to Vt.

template <bool OUT_BF16, bool QKV_BIAS>
__global__ __launch_bounds__(128) void gemm_bt(
    const bf16* __restrict__ A, const bf16* __restrict__ Bt,
    const float* __restrict__ b0, const float* __restrict__ b1,
    const float* __restrict__ b2, void* __restrict__ Cv, bf16* __restrict__ Vt,
    int M, int N, int K, int nbx, int bands_per_xcd)
{
    __shared__ bf16 As[4][64 * 32];
    __shared__ bf16 Bs[4][64 * 32];
    const int blk = blockIdx.x;
    const int xcd = blk & 7;
    const int s   = blk >> 3;
    const int m0 = (xcd * bands_per_xcd + s / nbx) * 64;
    const int n0 = (s % nbx) * 64;
    const int tid  = threadIdx.x;
    const int w    = tid >> 6, lane = tid & 63;
    const int quad = lane >> 4, l16 = lane & 15;

    f32x4 acc[4][2] = {};

    // staging: seg id in [0,256) per operand tile; 16 B per seg
    const int segA0 = w * 128 + lane;          // inst t=0
    const int segA1 = w * 128 + 64 + lane;     // inst t=1
    const bf16* gA0 = A  + (size_t)(m0 + (segA0 >> 2)) * K + (segA0 & 3) * 8;
    const bf16* gA1 = A  + (size_t)(m0 + (segA1 >> 2)) * K + (segA1 & 3) * 8;
    const bf16* gB0 = Bt + (size_t)(n0 + (segA0 >> 2)) * K + (segA0 & 3) * 8;
    const bf16* gB1 = Bt + (size_t)(n0 + (segA1 >> 2)) * K + (segA1 & 3) * 8;
    const int dA0 = segA0 * 8, dA1 = segA1 * 8;   // element offsets in LDS tile

    // prologue: stage kt=0,1,2 -> buf 0,1,2 (12 wave-loads in flight)
#pragma unroll
    for (int g = 0; g < 3; ++g) {
        gload_lds16(gA0 + g * 32, &As[g][0] + dA0);
        gload_lds16(gA1 + g * 32, &As[g][0] + dA1);
        gload_lds16(gB0 + g * 32, &Bs[g][0] + dA0);
        gload_lds16(gB1 + g * 32, &Bs[g][0] + dA1);
    }

    const int raoff = l16 * 32 + quad * 8;               // A frag base (row i*16+l16)
    const int rboff = (w * 32 + l16) * 32 + quad * 8;    // B frag base (col w*32+j*16+l16)

    const int nk = K >> 5;
    for (int kt = 0; kt < nk; ++kt) {
        if (kt + 3 < nk)      asm volatile("s_waitcnt vmcnt(8)" ::: "memory");
        else if (kt + 2 < nk) asm volatile("s_waitcnt vmcnt(4)" ::: "memory");
        else                  asm volatile("s_waitcnt vmcnt(0)" ::: "memory");
        asm volatile("s_barrier" ::: "memory");
        if (kt + 3 < nk) {
            bf16* At = &As[(kt + 3) & 3][0];
            bf16* Bt_ = &Bs[(kt + 3) & 3][0];
            gload_lds16(gA0 + (kt + 3) * 32, At + dA0);
            gload_lds16(gA1 + (kt + 3) * 32, At + dA1);
            gload_lds16(gB0 + (kt + 3) * 32, Bt_ + dA0);
            gload_lds16(gB1 + (kt + 3) * 32, Bt_ + dA1);
        }
        const bf16* Ac = &As[kt & 3][0];
        const bf16* Bc = &Bs[kt & 3][0];
        bf16x8 af[4], bfr[2];
#pragma unroll
        for (int i = 0; i < 4; ++i)
            af[i] = *(const bf16x8*)(Ac + raoff + i * 16 * 32);
#pragma unroll
        for (int j = 0; j < 2; ++j)
            bfr[j] = *(const bf16x8*)(Bc + rboff + j * 16 * 32);
#pragma unroll
        for (int i = 0; i < 4; ++i)
#pragma unroll
            for (int j = 0; j < 2; ++j)
                acc[i][j] = __builtin_amdgcn_mfma_f32_16x16x32_bf16(af[i], bfr[j], acc[i][j], 0, 0, 0);
    }

    const bool vtile = QKV_BIAS && (n0 >= 1280);
#pragma unroll
    for (int i = 0; i < 4; ++i)
#pragma unroll
        for (int j = 0; j < 2; ++j) {
            const int col = n0 + w * 32 + j * 16 + l16;
            const float bb = QKV_BIAS
                ? (col < 1024 ? b0[col] : (col < 1280 ? b1[col - 1024] : b2[col - 1280]))
                : b0[col];
            const int row0 = m0 + i * 16 + quad * 4;
            if (vtile) {
                bf16x4 pv;
#pragma unroll
                for (int r = 0; r < 4; ++r) pv[r] = (bf16)(acc[i][j][r] + bb);
                *(bf16x4*)&Vt[(size_t)(col - 1280) * VT_LD + row0] = pv;
            } else {
#pragma unroll
                for (int r = 0; r < 4; ++r) {
                    const float v = acc[i][j][r] + bb;
                    if (OUT_BF16) ((bf16*)Cv)[(size_t)(row0 + r) * N + col] = (bf16)v;
                    else          ((float*)Cv)[(size_t)(row0 + r) * N + col] = v;
                }
            }
        }
}

// ---------------- attention: 4 waves/block, 1 wave per (16-query tile, head) --
// Window <= 272 keys -> 17 S tiles of 16, PV over 9 K-chunks of 32.

__global__ __launch_bounds__(256) void attn_kernel(
    const bf16* __restrict__ QKV, const bf16* __restrict__ Vt, bf16* __restrict__ Oa)
{
    __shared__ bf16 Ps[4][16][296];   // per-wave P tile; 592 B rows: 2-way alias only
    const int wave = threadIdx.x >> 6;
    const int lane = threadIdx.x & 63;
    const int q0 = (blockIdx.x * 4 + wave) * 16;
    const int h  = blockIdx.y;
    const int kh = h >> 2;                     // GQA: head h -> kv head h/4
    const int quad = lane >> 4, l16 = lane & 15;
    const float slope = exp2f(-0.5f * (float)(h + 1));   // NH=16 ALiBi slopes
    const int lo = (q0 >= 256) ? (q0 - 256) : 0;          // window start

    // Q A-fragments (k-chunks 0 and 32 of HD=64)
    const bf16* qp = QKV + (size_t)(q0 + l16) * QKV_LD + h * 64 + quad * 8;
    bf16x8 qf0 = *(const bf16x8*)qp;
    bf16x8 qf1 = *(const bf16x8*)(qp + 32);

    // S = Q K^T : 17 tiles of 16 keys, fully unrolled so s[] stays in VGPRs
    f32x4 s[17];
#pragma unroll
    for (int t = 0; t < 17; ++t) {
        const bf16* kp = QKV + (size_t)(lo + t * 16 + l16) * QKV_LD + D_MODEL + kh * 64 + quad * 8;
        bf16x8 kf0 = *(const bf16x8*)kp;
        bf16x8 kf1 = *(const bf16x8*)(kp + 32);
        f32x4 a = {};
        a = __builtin_amdgcn_mfma_f32_16x16x32_bf16(qf0, kf0, a, 0, 0, 0);
        a = __builtin_amdgcn_mfma_f32_16x16x32_bf16(qf1, kf1, a, 0, 0, 0);
        s[t] = a;
    }

    // masked ALiBi softmax; lane holds rows quad*4+r at col l16 of each tile
    float rinv[4];
#pragma unroll
    for (int r = 0; r < 4; ++r) {
        const int row = q0 + quad * 4 + r;
        float mx = -1e30f;
#pragma unroll
        for (int t = 0; t < 17; ++t) {
            const int key = lo + t * 16 + l16;
            float v = s[t][r] * 0.125f - slope * (float)(row - key);
            const bool ok = (key <= row) && (key > row - WINDOW);
            v = ok ? v : -1e30f;
            s[t][r] = v;
            mx = fmaxf(mx, v);
        }
#pragma unroll
        for (int d = 1; d < 16; d <<= 1) mx = fmaxf(mx, __shfl_xor(mx, d));
        float sum = 0.f;
#pragma unroll
        for (int t = 0; t < 17; ++t) {
            float p = __expf(s[t][r] - mx);
            s[t][r] = p;
            sum += p;
        }
#pragma unroll
        for (int d = 1; d < 16; d <<= 1) sum += __shfl_xor(sum, d);
        rinv[r] = 1.f / sum;
    }

    // zero pad cols [272,288) (PV reads 288 cols)
    {
        int idx = lane;
#pragma unroll
        for (int it = 0; it < 4; ++it) {
            Ps[wave][(idx >> 4) & 15][272 + (idx & 15)] = (bf16)0.f;
            idx += 64;
        }
    }
    // P: C-layout regs -> LDS -> A-layout frags
#pragma unroll
    for (int t = 0; t < 17; ++t)
#pragma unroll
        for (int r = 0; r < 4; ++r)
            Ps[wave][quad * 4 + r][t * 16 + l16] = (bf16)(s[t][r] * rinv[r]);
    __syncthreads();

    // O = P V : V B-frags straight from global Vt (contiguous along keys)
    f32x4 o[4] = {};
#pragma unroll
    for (int c = 0; c < 9; ++c) {
        bf16x8 pf = *(const bf16x8*)&Ps[wave][l16][c * 32 + quad * 8];
#pragma unroll
        for (int j = 0; j < 4; ++j) {
            const bf16* vp = Vt + (size_t)(kh * 64 + j * 16 + l16) * VT_LD + lo + c * 32 + quad * 8;
            bf16x8 vf = *(const bf16x8*)vp;
            o[j] = __builtin_amdgcn_mfma_f32_16x16x32_bf16(pf, vf, o[j], 0, 0, 0);
        }
    }

#pragma unroll
    for (int j = 0; j < 4; ++j)
#pragma unroll
        for (int r = 0; r < 4; ++r)
            Oa[(size_t)(q0 + quad * 4 + r) * D_MODEL + h * 64 + j * 16 + l16] = (bf16)o[j][r];
}

// ---------------- launch ----------------

extern "C" void kernel_launch(void* const* d_in, const int* in_sizes, int n_in,
                              void* d_out, int out_size, void* d_ws, size_t ws_size,
                              hipStream_t stream) {
    const float* x  = (const float*)d_in[0];
    const float* Wq = (const float*)d_in[1];
    const float* bq = (const float*)d_in[2];
    const float* Wk = (const float*)d_in[3];
    const float* bk = (const float*)d_in[4];
    const float* Wv = (const float*)d_in[5];
    const float* bv = (const float*)d_in[6];
    const float* Wo = (const float*)d_in[7];
    const float* bo = (const float*)d_in[8];
    float* out = (float*)d_out;

    char* ws = (char*)d_ws;
    bf16*  xb    = (bf16*)(ws);                    // 4096x1024 bf16   (8 MB)
    bf16*  WtQKV = (bf16*)(ws + 8388608);          // 1536x1024 bf16   (3 MB)
    bf16*  WtO   = (bf16*)(ws + 11534336);         // 1024x1024 bf16   (2 MB)
    bf16*  QKV   = (bf16*)(ws + 13637632);         // 4096x1536 bf16   (12 MB; V region unused)
    bf16*  Vt    = (bf16*)(ws + 26220544);         // 256xVT_LD bf16   (~2 MB)
    bf16*  AO    = (bf16*)(ws + 28334080);         // 4096x1024 bf16   (8 MB) -> end ~35 MB

    prep_fused<<<4608, 256, 0, stream>>>(x, Wq, Wk, Wv, Wo, xb, WtQKV, WtO);

    gemm_bt<true, true><<<1536, 128, 0, stream>>>(
        xb, WtQKV, bq, bk, bv, QKV, Vt, 4096, 1536, 1024, 24, 8);

    attn_kernel<<<dim3(64, 16), 256, 0, stream>>>(QKV, Vt, AO);

    gemm_bt<false, false><<<1024, 128, 0, stream>>>(
        AO, WtO, bo, nullptr, nullptr, out, nullptr, 4096, 1024, 1024, 16, 8);
}

// Round 12
// 177.075 us; speedup vs baseline: 1.0447x; 1.0447x over previous
//
#include <hip/hip_runtime.h>

typedef __bf16 bf16;
typedef __bf16 bf16x4 __attribute__((ext_vector_type(4)));
typedef __bf16 bf16x8 __attribute__((ext_vector_type(8)));
typedef float f32x4 __attribute__((ext_vector_type(4)));

#define T_LEN   4096
#define D_MODEL 1024
#define QKV_LD  1536
#define VT_LD   4128   // 4096 + 32 pad: last tile's PV chunk over-reads into pad (x0 P)
#define WINDOW  256

// async global->LDS, 16 B per lane; data lands at readfirstlane(l) + lane*16
__device__ __forceinline__ void gload_lds16(const bf16* g, bf16* l) {
    __builtin_amdgcn_global_load_lds((const __attribute__((address_space(1))) void*)g,
                                     (__attribute__((address_space(3))) void*)l, 16, 0, 0);
}

// ---------------- fused prep: x->bf16, Wq|Wk|Wv transpose, Wo transpose -----
// grid sections: [0,2048) cvt, [2048,3584) wqkv, [3584,4608) wo

__global__ __launch_bounds__(256) void prep_fused(
    const float* __restrict__ x,
    const float* __restrict__ Wq, const float* __restrict__ Wk,
    const float* __restrict__ Wv, const float* __restrict__ Wo,
    bf16* __restrict__ xb, bf16* __restrict__ WtQKV, bf16* __restrict__ WtO)
{
    __shared__ float t[32][33];
    const int blk = blockIdx.x;
    if (blk < 2048) {                       // ---- x (f32) -> xb (bf16)
        int i = (blk * 256 + threadIdx.x) * 8;
        float4 a = *(const float4*)(x + i);
        float4 b = *(const float4*)(x + i + 4);
        bf16x8 o;
        o[0] = (bf16)a.x; o[1] = (bf16)a.y; o[2] = (bf16)a.z; o[3] = (bf16)a.w;
        o[4] = (bf16)b.x; o[5] = (bf16)b.y; o[6] = (bf16)b.z; o[7] = (bf16)b.w;
        *(bf16x8*)(xb + i) = o;
        return;
    }
    const float* W; bf16* Wt; int n0, k0, Ns, nofs;
    if (blk < 3584) {                       // ---- Wq|Wk|Wv -> WtQKV (1536x1024)
        int b = blk - 2048;
        n0 = (b % 48) * 32; k0 = (b / 48) * 32;
        if (n0 < 1024)      { W = Wq; Ns = 1024; nofs = 0; }
        else if (n0 < 1280) { W = Wk; Ns = 256;  nofs = 1024; }
        else                { W = Wv; Ns = 256;  nofs = 1280; }
        Wt = WtQKV;
    } else {                                // ---- Wo -> WtO (1024x1024)
        int b = blk - 3584;
        n0 = (b % 32) * 32; k0 = (b / 32) * 32;
        W = Wo; Ns = 1024; nofs = 0; Wt = WtO;
    }
    int tx = threadIdx.x & 31, ty = threadIdx.x >> 5;
#pragma unroll
    for (int it = 0; it < 4; ++it)
        t[ty + it * 8][tx] = W[(size_t)(k0 + ty + it * 8) * Ns + (n0 - nofs) + tx];
    __syncthreads();
#pragma unroll
    for (int it = 0; it < 4; ++it)
        Wt[(size_t)(n0 + ty + it * 8) * 1024 + k0 + tx] = (bf16)t[tx][ty + it * 8];
}

// ---------------- GEMM1 (R9 exact): C = A*Bt^T + bias -----------------------
// 128 threads = 2 waves; block tile 64x64, wave tile 64x32 (acc 4x2).
// LDS 3 x (4KB A + 4KB B) = 24 KB -> 6 blocks/CU. 3-buffer pipeline, raw
// s_barrier + partial vmcnt. XCD swizzle: blk&7 = XCD, bands pinned per XCD.
// QKV_BIAS: col-blocks n0>=1280 are V -> written transposed to Vt.

template <bool OUT_BF16, bool QKV_BIAS>
__global__ __launch_bounds__(128) void gemm_bt(
    const bf16* __restrict__ A, const bf16* __restrict__ Bt,
    const float* __restrict__ b0, const float* __restrict__ b1,
    const float* __restrict__ b2, void* __restrict__ Cv, bf16* __restrict__ Vt,
    int M, int N, int K, int nbx, int bands_per_xcd)
{
    __shared__ bf16 As[3][64 * 32];
    __shared__ bf16 Bs[3][64 * 32];
    const int blk = blockIdx.x;
    const int xcd = blk & 7;
    const int s   = blk >> 3;
    const int m0 = (xcd * bands_per_xcd + s / nbx) * 64;
    const int n0 = (s % nbx) * 64;
    const int tid  = threadIdx.x;
    const int w    = tid >> 6, lane = tid & 63;
    const int quad = lane >> 4, l16 = lane & 15;

    f32x4 acc[4][2] = {};

    // staging: seg id in [0,256) per operand tile; 16 B per seg
    const int segA0 = w * 128 + lane;          // inst t=0
    const int segA1 = w * 128 + 64 + lane;     // inst t=1
    const bf16* gA0 = A  + (size_t)(m0 + (segA0 >> 2)) * K + (segA0 & 3) * 8;
    const bf16* gA1 = A  + (size_t)(m0 + (segA1 >> 2)) * K + (segA1 & 3) * 8;
    const bf16* gB0 = Bt + (size_t)(n0 + (segA0 >> 2)) * K + (segA0 & 3) * 8;
    const bf16* gB1 = Bt + (size_t)(n0 + (segA1 >> 2)) * K + (segA1 & 3) * 8;
    const int dA0 = segA0 * 8, dA1 = segA1 * 8;   // element offsets in LDS tile

    int bc = 0, bn = 1, bo = 2;   // current / next / overwrite buffer ids

    // prologue: stage kt=0 -> buf0, kt=1 -> buf1 (8 wave-loads in flight)
    gload_lds16(gA0,      &As[0][0] + dA0);
    gload_lds16(gA1,      &As[0][0] + dA1);
    gload_lds16(gB0,      &Bs[0][0] + dA0);
    gload_lds16(gB1,      &Bs[0][0] + dA1);
    gload_lds16(gA0 + 32, &As[1][0] + dA0);
    gload_lds16(gA1 + 32, &As[1][0] + dA1);
    gload_lds16(gB0 + 32, &Bs[1][0] + dA0);
    gload_lds16(gB1 + 32, &Bs[1][0] + dA1);

    const int raoff = l16 * 32 + quad * 8;               // A frag base (row i*16+l16)
    const int rboff = (w * 32 + l16) * 32 + quad * 8;    // B frag base (col w*32+j*16+l16)

    const int nk = K >> 5;
    for (int kt = 0; kt < nk; ++kt) {
        if (kt + 1 < nk) asm volatile("s_waitcnt vmcnt(4)" ::: "memory");
        else             asm volatile("s_waitcnt vmcnt(0)" ::: "memory");
        asm volatile("s_barrier" ::: "memory");
        if (kt + 2 < nk) {
            gload_lds16(gA0 + (kt + 2) * 32, &As[bo][0] + dA0);
            gload_lds16(gA1 + (kt + 2) * 32, &As[bo][0] + dA1);
            gload_lds16(gB0 + (kt + 2) * 32, &Bs[bo][0] + dA0);
            gload_lds16(gB1 + (kt + 2) * 32, &Bs[bo][0] + dA1);
        }
        const bf16* Ac = &As[bc][0];
        const bf16* Bc = &Bs[bc][0];
        bf16x8 af[4], bfr[2];
#pragma unroll
        for (int i = 0; i < 4; ++i)
            af[i] = *(const bf16x8*)(Ac + raoff + i * 16 * 32);
#pragma unroll
        for (int j = 0; j < 2; ++j)
            bfr[j] = *(const bf16x8*)(Bc + rboff + j * 16 * 32);
#pragma unroll
        for (int i = 0; i < 4; ++i)
#pragma unroll
            for (int j = 0; j < 2; ++j)
                acc[i][j] = __builtin_amdgcn_mfma_f32_16x16x32_bf16(af[i], bfr[j], acc[i][j], 0, 0, 0);
        int t = bc; bc = bn; bn = bo; bo = t;
    }

    const bool vtile = QKV_BIAS && (n0 >= 1280);
#pragma unroll
    for (int i = 0; i < 4; ++i)
#pragma unroll
        for (int j = 0; j < 2; ++j) {
            const int col = n0 + w * 32 + j * 16 + l16;
            const float bb = QKV_BIAS
                ? (col < 1024 ? b0[col] : (col < 1280 ? b1[col - 1024] : b2[col - 1280]))
                : b0[col];
            const int row0 = m0 + i * 16 + quad * 4;
            if (vtile) {
                bf16x4 pv;
#pragma unroll
                for (int r = 0; r < 4; ++r) pv[r] = (bf16)(acc[i][j][r] + bb);
                *(bf16x4*)&Vt[(size_t)(col - 1280) * VT_LD + row0] = pv;
            } else {
#pragma unroll
                for (int r = 0; r < 4; ++r) {
                    const float v = acc[i][j][r] + bb;
                    if (OUT_BF16) ((bf16*)Cv)[(size_t)(row0 + r) * N + col] = (bf16)v;
                    else          ((float*)Cv)[(size_t)(row0 + r) * N + col] = v;
                }
            }
        }
}

// ---------------- GEMM2: SINGLE-WAVE, BARRIER-FREE ---------------------------
// 64 threads = 1 wave; tile 64x64 (wave IS the block) -> NO s_barrier anywhere:
// the wave's global_load_lds -> s_waitcnt vmcnt(N) -> ds_read chain is
// self-consistent, so the partial-vmcnt pipeline cannot be defeated by
// barrier-drain semantics (m131's failure mode needs a barrier).
// 3 buffers x (4KB A + 4KB B) = 24 KB. Per iter: 8 staging loads, 8
// ds_read_b128, 16 MFMA (m97 wave ratio). Ladder: prologue 16 in flight;
// iter kt waits vmcnt(8) (own 8 oldest = buffer kt landed), stages kt+2;
// last iter waits vmcnt(0). Buffer recycle safe: iter kt-1's ds_reads
// completed (lgkm-waited before their MFMAs) before kt's staging issues.

__global__ __launch_bounds__(64) void gemm_sw(
    const bf16* __restrict__ A, const bf16* __restrict__ Bt,
    const float* __restrict__ b0, float* __restrict__ Cv,
    int M, int N, int K, int nbx, int bands_per_xcd)
{
    __shared__ bf16 As[3][64 * 32];
    __shared__ bf16 Bs[3][64 * 32];
    const int blk = blockIdx.x;
    const int xcd = blk & 7;
    const int s   = blk >> 3;
    const int m0 = (xcd * bands_per_xcd + s / nbx) * 64;
    const int n0 = (s % nbx) * 64;
    const int lane = threadIdx.x;
    const int quad = lane >> 4, l16 = lane & 15;

    f32x4 acc[4][4] = {};

    // staging: 256 segs of 16 B per operand tile; lane handles segs t*64+lane
    const bf16* gA[4]; const bf16* gB[4]; int dd[4];
#pragma unroll
    for (int t = 0; t < 4; ++t) {
        const int seg = t * 64 + lane;
        gA[t] = A  + (size_t)(m0 + (seg >> 2)) * K + (seg & 3) * 8;
        gB[t] = Bt + (size_t)(n0 + (seg >> 2)) * K + (seg & 3) * 8;
        dd[t] = seg * 8;
    }

    // prologue: stage kt=0 -> buf0, kt=1 -> buf1 (16 loads in flight)
#pragma unroll
    for (int g = 0; g < 2; ++g)
#pragma unroll
        for (int t = 0; t < 4; ++t) {
            gload_lds16(gA[t] + g * 32, &As[g][0] + dd[t]);
            gload_lds16(gB[t] + g * 32, &Bs[g][0] + dd[t]);
        }

    const int raoff = l16 * 32 + quad * 8;
    const int rboff = l16 * 32 + quad * 8;

    const int nk = K >> 5;
    for (int kt = 0; kt < nk; ++kt) {
        if (kt + 1 < nk) asm volatile("s_waitcnt vmcnt(8)" ::: "memory");
        else             asm volatile("s_waitcnt vmcnt(0)" ::: "memory");
        if (kt + 2 < nk) {
            bf16* At = &As[(kt + 2) % 3][0];
            bf16* Bd = &Bs[(kt + 2) % 3][0];
#pragma unroll
            for (int t = 0; t < 4; ++t) {
                gload_lds16(gA[t] + (kt + 2) * 32, At + dd[t]);
                gload_lds16(gB[t] + (kt + 2) * 32, Bd + dd[t]);
            }
        }
        const bf16* Ac = &As[kt % 3][0];
        const bf16* Bc = &Bs[kt % 3][0];
        bf16x8 af[4], bfr[4];
#pragma unroll
        for (int i = 0; i < 4; ++i)
            af[i] = *(const bf16x8*)(Ac + raoff + i * 16 * 32);
#pragma unroll
        for (int j = 0; j < 4; ++j)
            bfr[j] = *(const bf16x8*)(Bc + rboff + j * 16 * 32);
#pragma unroll
        for (int i = 0; i < 4; ++i)
#pragma unroll
            for (int j = 0; j < 4; ++j)
                acc[i][j] = __builtin_amdgcn_mfma_f32_16x16x32_bf16(af[i], bfr[j], acc[i][j], 0, 0, 0);
    }

#pragma unroll
    for (int i = 0; i < 4; ++i)
#pragma unroll
        for (int j = 0; j < 4; ++j) {
            const int col = n0 + j * 16 + l16;
            const float bb = b0[col];
            const int row0 = m0 + i * 16 + quad * 4;
#pragma unroll
            for (int r = 0; r < 4; ++r)
                Cv[(size_t)(row0 + r) * N + col] = acc[i][j][r] + bb;
        }
}

// ---------------- attention: 4 waves/block, 1 wave per (16-query tile, head) --
// Window <= 272 keys -> 17 S tiles of 16, PV over 9 K-chunks of 32.

__global__ __launch_bounds__(256) void attn_kernel(
    const bf16* __restrict__ QKV, const bf16* __restrict__ Vt, bf16* __restrict__ Oa)
{
    __shared__ bf16 Ps[4][16][296];   // per-wave P tile; 592 B rows: 2-way alias only
    const int wave = threadIdx.x >> 6;
    const int lane = threadIdx.x & 63;
    const int q0 = (blockIdx.x * 4 + wave) * 16;
    const int h  = blockIdx.y;
    const int kh = h >> 2;                     // GQA: head h -> kv head h/4
    const int quad = lane >> 4, l16 = lane & 15;
    const float slope = exp2f(-0.5f * (float)(h + 1));   // NH=16 ALiBi slopes
    const int lo = (q0 >= 256) ? (q0 - 256) : 0;          // window start

    // Q A-fragments (k-chunks 0 and 32 of HD=64)
    const bf16* qp = QKV + (size_t)(q0 + l16) * QKV_LD + h * 64 + quad * 8;
    bf16x8 qf0 = *(const bf16x8*)qp;
    bf16x8 qf1 = *(const bf16x8*)(qp + 32);

    // S = Q K^T : 17 tiles of 16 keys, fully unrolled so s[] stays in VGPRs
    f32x4 s[17];
#pragma unroll
    for (int t = 0; t < 17; ++t) {
        const bf16* kp = QKV + (size_t)(lo + t * 16 + l16) * QKV_LD + D_MODEL + kh * 64 + quad * 8;
        bf16x8 kf0 = *(const bf16x8*)kp;
        bf16x8 kf1 = *(const bf16x8*)(kp + 32);
        f32x4 a = {};
        a = __builtin_amdgcn_mfma_f32_16x16x32_bf16(qf0, kf0, a, 0, 0, 0);
        a = __builtin_amdgcn_mfma_f32_16x16x32_bf16(qf1, kf1, a, 0, 0, 0);
        s[t] = a;
    }

    // masked ALiBi softmax; lane holds rows quad*4+r at col l16 of each tile
    float rinv[4];
#pragma unroll
    for (int r = 0; r < 4; ++r) {
        const int row = q0 + quad * 4 + r;
        float mx = -1e30f;
#pragma unroll
        for (int t = 0; t < 17; ++t) {
            const int key = lo + t * 16 + l16;
            float v = s[t][r] * 0.125f - slope * (float)(row - key);
            const bool ok = (key <= row) && (key > row - WINDOW);
            v = ok ? v : -1e30f;
            s[t][r] = v;
            mx = fmaxf(mx, v);
        }
#pragma unroll
        for (int d = 1; d < 16; d <<= 1) mx = fmaxf(mx, __shfl_xor(mx, d));
        float sum = 0.f;
#pragma unroll
        for (int t = 0; t < 17; ++t) {
            float p = __expf(s[t][r] - mx);
            s[t][r] = p;
            sum += p;
        }
#pragma unroll
        for (int d = 1; d < 16; d <<= 1) sum += __shfl_xor(sum, d);
        rinv[r] = 1.f / sum;
    }

    // zero pad cols [272,288) (PV reads 288 cols)
    {
        int idx = lane;
#pragma unroll
        for (int it = 0; it < 4; ++it) {
            Ps[wave][(idx >> 4) & 15][272 + (idx & 15)] = (bf16)0.f;
            idx += 64;
        }
    }
    // P: C-layout regs -> LDS -> A-layout frags
#pragma unroll
    for (int t = 0; t < 17; ++t)
#pragma unroll
        for (int r = 0; r < 4; ++r)
            Ps[wave][quad * 4 + r][t * 16 + l16] = (bf16)(s[t][r] * rinv[r]);
    __syncthreads();

    // O = P V : V B-frags straight from global Vt (contiguous along keys)
    f32x4 o[4] = {};
#pragma unroll
    for (int c = 0; c < 9; ++c) {
        bf16x8 pf = *(const bf16x8*)&Ps[wave][l16][c * 32 + quad * 8];
#pragma unroll
        for (int j = 0; j < 4; ++j) {
            const bf16* vp = Vt + (size_t)(kh * 64 + j * 16 + l16) * VT_LD + lo + c * 32 + quad * 8;
            bf16x8 vf = *(const bf16x8*)vp;
            o[j] = __builtin_amdgcn_mfma_f32_16x16x32_bf16(pf, vf, o[j], 0, 0, 0);
        }
    }

#pragma unroll
    for (int j = 0; j < 4; ++j)
#pragma unroll
        for (int r = 0; r < 4; ++r)
            Oa[(size_t)(q0 + quad * 4 + r) * D_MODEL + h * 64 + j * 16 + l16] = (bf16)o[j][r];
}

// ---------------- launch ----------------

extern "C" void kernel_launch(void* const* d_in, const int* in_sizes, int n_in,
                              void* d_out, int out_size, void* d_ws, size_t ws_size,
                              hipStream_t stream) {
    const float* x  = (const float*)d_in[0];
    const float* Wq = (const float*)d_in[1];
    const float* bq = (const float*)d_in[2];
    const float* Wk = (const float*)d_in[3];
    const float* bk = (const float*)d_in[4];
    const float* Wv = (const float*)d_in[5];
    const float* bv = (const float*)d_in[6];
    const float* Wo = (const float*)d_in[7];
    const float* bo = (const float*)d_in[8];
    float* out = (float*)d_out;

    char* ws = (char*)d_ws;
    bf16*  xb    = (bf16*)(ws);                    // 4096x1024 bf16   (8 MB)
    bf16*  WtQKV = (bf16*)(ws + 8388608);          // 1536x1024 bf16   (3 MB)
    bf16*  WtO   = (bf16*)(ws + 11534336);         // 1024x1024 bf16   (2 MB)
    bf16*  QKV   = (bf16*)(ws + 13637632);         // 4096x1536 bf16   (12 MB; V region unused)
    bf16*  Vt    = (bf16*)(ws + 26220544);         // 256xVT_LD bf16   (~2 MB)
    bf16*  AO    = (bf16*)(ws + 28334080);         // 4096x1024 bf16   (8 MB) -> end ~35 MB

    prep_fused<<<4608, 256, 0, stream>>>(x, Wq, Wk, Wv, Wo, xb, WtQKV, WtO);

    gemm_bt<true, true><<<1536, 128, 0, stream>>>(
        xb, WtQKV, bq, bk, bv, QKV, Vt, 4096, 1536, 1024, 24, 8);

    attn_kernel<<<dim3(64, 16), 256, 0, stream>>>(QKV, Vt, AO);

    gemm_sw<<<1024, 64, 0, stream>>>(AO, WtO, bo, out, 4096, 1024, 1024, 16, 8);
}

// Round 13
// 175.017 us; speedup vs baseline: 1.0569x; 1.0118x over previous
//
#include <hip/hip_runtime.h>

typedef __bf16 bf16;
typedef __bf16 bf16x4 __attribute__((ext_vector_type(4)));
typedef __bf16 bf16x8 __attribute__((ext_vector_type(8)));
typedef float f32x4 __attribute__((ext_vector_type(4)));

#define T_LEN   4096
#define D_MODEL 1024
#define QKV_LD  1536
#define VT_LD   4128   // 4096 + 32 pad: last tile's PV chunk over-reads into pad (x0 P)
#define WINDOW  256

// async global->LDS, 16 B per lane; data lands at readfirstlane(l) + lane*16
__device__ __forceinline__ void gload_lds16(const bf16* g, bf16* l) {
    __builtin_amdgcn_global_load_lds((const __attribute__((address_space(1))) void*)g,
                                     (__attribute__((address_space(3))) void*)l, 16, 0, 0);
}

// ---------------- fused prep: x->bf16, Wq|Wk|Wv transpose, Wo transpose -----
// grid sections: [0,2048) cvt, [2048,3584) wqkv, [3584,4608) wo

__global__ __launch_bounds__(256) void prep_fused(
    const float* __restrict__ x,
    const float* __restrict__ Wq, const float* __restrict__ Wk,
    const float* __restrict__ Wv, const float* __restrict__ Wo,
    bf16* __restrict__ xb, bf16* __restrict__ WtQKV, bf16* __restrict__ WtO)
{
    __shared__ float t[32][33];
    const int blk = blockIdx.x;
    if (blk < 2048) {                       // ---- x (f32) -> xb (bf16)
        int i = (blk * 256 + threadIdx.x) * 8;
        float4 a = *(const float4*)(x + i);
        float4 b = *(const float4*)(x + i + 4);
        bf16x8 o;
        o[0] = (bf16)a.x; o[1] = (bf16)a.y; o[2] = (bf16)a.z; o[3] = (bf16)a.w;
        o[4] = (bf16)b.x; o[5] = (bf16)b.y; o[6] = (bf16)b.z; o[7] = (bf16)b.w;
        *(bf16x8*)(xb + i) = o;
        return;
    }
    const float* W; bf16* Wt; int n0, k0, Ns, nofs;
    if (blk < 3584) {                       // ---- Wq|Wk|Wv -> WtQKV (1536x1024)
        int b = blk - 2048;
        n0 = (b % 48) * 32; k0 = (b / 48) * 32;
        if (n0 < 1024)      { W = Wq; Ns = 1024; nofs = 0; }
        else if (n0 < 1280) { W = Wk; Ns = 256;  nofs = 1024; }
        else                { W = Wv; Ns = 256;  nofs = 1280; }
        Wt = WtQKV;
    } else {                                // ---- Wo -> WtO (1024x1024)
        int b = blk - 3584;
        n0 = (b % 32) * 32; k0 = (b / 32) * 32;
        W = Wo; Ns = 1024; nofs = 0; Wt = WtO;
    }
    int tx = threadIdx.x & 31, ty = threadIdx.x >> 5;
#pragma unroll
    for (int it = 0; it < 4; ++it)
        t[ty + it * 8][tx] = W[(size_t)(k0 + ty + it * 8) * Ns + (n0 - nofs) + tx];
    __syncthreads();
#pragma unroll
    for (int it = 0; it < 4; ++it)
        Wt[(size_t)(n0 + ty + it * 8) * 1024 + k0 + tx] = (bf16)t[tx][ty + it * 8];
}

// ---------------- GEMM (R9 exact): C(MxN) = A(MxK)*Bt(NxK)^T + bias ---------
// 128 threads = 2 waves; block tile 64x64, wave tile 64x32 (acc 4x2).
// LDS 3 x (4KB A + 4KB B) = 24 KB -> 6 blocks/CU (12 waves/CU). 3-buffer
// pipeline, raw s_barrier + partial vmcnt. XCD swizzle: blk&7 = XCD, bands
// pinned per XCD (A-band L2-resident across its column-blocks).
// QKV_BIAS: col-blocks n0>=1280 are V -> written transposed to Vt.
// NOTE (session ceiling): this GEMM family measures ~300 TF at K=1024 —
// on the m102 shape-curve plateau; 9 structural variants (vmcnt ladders,
// 4-buffer, barrier-free single-wave, no-LDS, fp8, tile/occupancy sweeps)
// all landed 171-228 us total. This config is the best measured.

template <bool OUT_BF16, bool QKV_BIAS>
__global__ __launch_bounds__(128) void gemm_bt(
    const bf16* __restrict__ A, const bf16* __restrict__ Bt,
    const float* __restrict__ b0, const float* __restrict__ b1,
    const float* __restrict__ b2, void* __restrict__ Cv, bf16* __restrict__ Vt,
    int M, int N, int K, int nbx, int bands_per_xcd)
{
    __shared__ bf16 As[3][64 * 32];
    __shared__ bf16 Bs[3][64 * 32];
    const int blk = blockIdx.x;
    const int xcd = blk & 7;
    const int s   = blk >> 3;
    const int m0 = (xcd * bands_per_xcd + s / nbx) * 64;
    const int n0 = (s % nbx) * 64;
    const int tid  = threadIdx.x;
    const int w    = tid >> 6, lane = tid & 63;
    const int quad = lane >> 4, l16 = lane & 15;

    f32x4 acc[4][2] = {};

    // staging: seg id in [0,256) per operand tile; 16 B per seg
    const int segA0 = w * 128 + lane;          // inst t=0
    const int segA1 = w * 128 + 64 + lane;     // inst t=1
    const bf16* gA0 = A  + (size_t)(m0 + (segA0 >> 2)) * K + (segA0 & 3) * 8;
    const bf16* gA1 = A  + (size_t)(m0 + (segA1 >> 2)) * K + (segA1 & 3) * 8;
    const bf16* gB0 = Bt + (size_t)(n0 + (segA0 >> 2)) * K + (segA0 & 3) * 8;
    const bf16* gB1 = Bt + (size_t)(n0 + (segA1 >> 2)) * K + (segA1 & 3) * 8;
    const int dA0 = segA0 * 8, dA1 = segA1 * 8;   // element offsets in LDS tile

    int bc = 0, bn = 1, bo = 2;   // current / next / overwrite buffer ids

    // prologue: stage kt=0 -> buf0, kt=1 -> buf1 (8 wave-loads in flight)
    gload_lds16(gA0,      &As[0][0] + dA0);
    gload_lds16(gA1,      &As[0][0] + dA1);
    gload_lds16(gB0,      &Bs[0][0] + dA0);
    gload_lds16(gB1,      &Bs[0][0] + dA1);
    gload_lds16(gA0 + 32, &As[1][0] + dA0);
    gload_lds16(gA1 + 32, &As[1][0] + dA1);
    gload_lds16(gB0 + 32, &Bs[1][0] + dA0);
    gload_lds16(gB1 + 32, &Bs[1][0] + dA1);

    const int raoff = l16 * 32 + quad * 8;               // A frag base (row i*16+l16)
    const int rboff = (w * 32 + l16) * 32 + quad * 8;    // B frag base (col w*32+j*16+l16)

    const int nk = K >> 5;
    for (int kt = 0; kt < nk; ++kt) {
        if (kt + 1 < nk) asm volatile("s_waitcnt vmcnt(4)" ::: "memory");
        else             asm volatile("s_waitcnt vmcnt(0)" ::: "memory");
        asm volatile("s_barrier" ::: "memory");
        if (kt + 2 < nk) {
            gload_lds16(gA0 + (kt + 2) * 32, &As[bo][0] + dA0);
            gload_lds16(gA1 + (kt + 2) * 32, &As[bo][0] + dA1);
            gload_lds16(gB0 + (kt + 2) * 32, &Bs[bo][0] + dA0);
            gload_lds16(gB1 + (kt + 2) * 32, &Bs[bo][0] + dA1);
        }
        const bf16* Ac = &As[bc][0];
        const bf16* Bc = &Bs[bc][0];
        bf16x8 af[4], bfr[2];
#pragma unroll
        for (int i = 0; i < 4; ++i)
            af[i] = *(const bf16x8*)(Ac + raoff + i * 16 * 32);
#pragma unroll
        for (int j = 0; j < 2; ++j)
            bfr[j] = *(const bf16x8*)(Bc + rboff + j * 16 * 32);
#pragma unroll
        for (int i = 0; i < 4; ++i)
#pragma unroll
            for (int j = 0; j < 2; ++j)
                acc[i][j] = __builtin_amdgcn_mfma_f32_16x16x32_bf16(af[i], bfr[j], acc[i][j], 0, 0, 0);
        int t = bc; bc = bn; bn = bo; bo = t;
    }

    const bool vtile = QKV_BIAS && (n0 >= 1280);
#pragma unroll
    for (int i = 0; i < 4; ++i)
#pragma unroll
        for (int j = 0; j < 2; ++j) {
            const int col = n0 + w * 32 + j * 16 + l16;
            const float bb = QKV_BIAS
                ? (col < 1024 ? b0[col] : (col < 1280 ? b1[col - 1024] : b2[col - 1280]))
                : b0[col];
            const int row0 = m0 + i * 16 + quad * 4;
            if (vtile) {
                bf16x4 pv;
#pragma unroll
                for (int r = 0; r < 4; ++r) pv[r] = (bf16)(acc[i][j][r] + bb);
                *(bf16x4*)&Vt[(size_t)(col - 1280) * VT_LD + row0] = pv;
            } else {
#pragma unroll
                for (int r = 0; r < 4; ++r) {
                    const float v = acc[i][j][r] + bb;
                    if (OUT_BF16) ((bf16*)Cv)[(size_t)(row0 + r) * N + col] = (bf16)v;
                    else          ((float*)Cv)[(size_t)(row0 + r) * N + col] = v;
                }
            }
        }
}

// ---------------- attention: 4 waves/block, 1 wave per (16-query tile, head) --
// Window <= 272 keys -> 17 S tiles of 16, PV over 9 K-chunks of 32.

__global__ __launch_bounds__(256) void attn_kernel(
    const bf16* __restrict__ QKV, const bf16* __restrict__ Vt, bf16* __restrict__ Oa)
{
    __shared__ bf16 Ps[4][16][296];   // per-wave P tile; 592 B rows: 2-way alias only
    const int wave = threadIdx.x >> 6;
    const int lane = threadIdx.x & 63;
    const int q0 = (blockIdx.x * 4 + wave) * 16;
    const int h  = blockIdx.y;
    const int kh = h >> 2;                     // GQA: head h -> kv head h/4
    const int quad = lane >> 4, l16 = lane & 15;
    const float slope = exp2f(-0.5f * (float)(h + 1));   // NH=16 ALiBi slopes
    const int lo = (q0 >= 256) ? (q0 - 256) : 0;          // window start

    // Q A-fragments (k-chunks 0 and 32 of HD=64)
    const bf16* qp = QKV + (size_t)(q0 + l16) * QKV_LD + h * 64 + quad * 8;
    bf16x8 qf0 = *(const bf16x8*)qp;
    bf16x8 qf1 = *(const bf16x8*)(qp + 32);

    // S = Q K^T : 17 tiles of 16 keys, fully unrolled so s[] stays in VGPRs
    f32x4 s[17];
#pragma unroll
    for (int t = 0; t < 17; ++t) {
        const bf16* kp = QKV + (size_t)(lo + t * 16 + l16) * QKV_LD + D_MODEL + kh * 64 + quad * 8;
        bf16x8 kf0 = *(const bf16x8*)kp;
        bf16x8 kf1 = *(const bf16x8*)(kp + 32);
        f32x4 a = {};
        a = __builtin_amdgcn_mfma_f32_16x16x32_bf16(qf0, kf0, a, 0, 0, 0);
        a = __builtin_amdgcn_mfma_f32_16x16x32_bf16(qf1, kf1, a, 0, 0, 0);
        s[t] = a;
    }

    // masked ALiBi softmax; lane holds rows quad*4+r at col l16 of each tile
    float rinv[4];
#pragma unroll
    for (int r = 0; r < 4; ++r) {
        const int row = q0 + quad * 4 + r;
        float mx = -1e30f;
#pragma unroll
        for (int t = 0; t < 17; ++t) {
            const int key = lo + t * 16 + l16;
            float v = s[t][r] * 0.125f - slope * (float)(row - key);
            const bool ok = (key <= row) && (key > row - WINDOW);
            v = ok ? v : -1e30f;
            s[t][r] = v;
            mx = fmaxf(mx, v);
        }
#pragma unroll
        for (int d = 1; d < 16; d <<= 1) mx = fmaxf(mx, __shfl_xor(mx, d));
        float sum = 0.f;
#pragma unroll
        for (int t = 0; t < 17; ++t) {
            float p = __expf(s[t][r] - mx);
            s[t][r] = p;
            sum += p;
        }
#pragma unroll
        for (int d = 1; d < 16; d <<= 1) sum += __shfl_xor(sum, d);
        rinv[r] = 1.f / sum;
    }

    // zero pad cols [272,288) (PV reads 288 cols)
    {
        int idx = lane;
#pragma unroll
        for (int it = 0; it < 4; ++it) {
            Ps[wave][(idx >> 4) & 15][272 + (idx & 15)] = (bf16)0.f;
            idx += 64;
        }
    }
    // P: C-layout regs -> LDS -> A-layout frags
#pragma unroll
    for (int t = 0; t < 17; ++t)
#pragma unroll
        for (int r = 0; r < 4; ++r)
            Ps[wave][quad * 4 + r][t * 16 + l16] = (bf16)(s[t][r] * rinv[r]);
    __syncthreads();

    // O = P V : V B-frags straight from global Vt (contiguous along keys)
    f32x4 o[4] = {};
#pragma unroll
    for (int c = 0; c < 9; ++c) {
        bf16x8 pf = *(const bf16x8*)&Ps[wave][l16][c * 32 + quad * 8];
#pragma unroll
        for (int j = 0; j < 4; ++j) {
            const bf16* vp = Vt + (size_t)(kh * 64 + j * 16 + l16) * VT_LD + lo + c * 32 + quad * 8;
            bf16x8 vf = *(const bf16x8*)vp;
            o[j] = __builtin_amdgcn_mfma_f32_16x16x32_bf16(pf, vf, o[j], 0, 0, 0);
        }
    }

#pragma unroll
    for (int j = 0; j < 4; ++j)
#pragma unroll
        for (int r = 0; r < 4; ++r)
            Oa[(size_t)(q0 + quad * 4 + r) * D_MODEL + h * 64 + j * 16 + l16] = (bf16)o[j][r];
}

// ---------------- launch ----------------

extern "C" void kernel_launch(void* const* d_in, const int* in_sizes, int n_in,
                              void* d_out, int out_size, void* d_ws, size_t ws_size,
                              hipStream_t stream) {
    const float* x  = (const float*)d_in[0];
    const float* Wq = (const float*)d_in[1];
    const float* bq = (const float*)d_in[2];
    const float* Wk = (const float*)d_in[3];
    const float* bk = (const float*)d_in[4];
    const float* Wv = (const float*)d_in[5];
    const float* bv = (const float*)d_in[6];
    const float* Wo = (const float*)d_in[7];
    const float* bo = (const float*)d_in[8];
    float* out = (float*)d_out;

    char* ws = (char*)d_ws;
    bf16*  xb    = (bf16*)(ws);                    // 4096x1024 bf16   (8 MB)
    bf16*  WtQKV = (bf16*)(ws + 8388608);          // 1536x1024 bf16   (3 MB)
    bf16*  WtO   = (bf16*)(ws + 11534336);         // 1024x1024 bf16   (2 MB)
    bf16*  QKV   = (bf16*)(ws + 13637632);         // 4096x1536 bf16   (12 MB; V region unused)
    bf16*  Vt    = (bf16*)(ws + 26220544);         // 256xVT_LD bf16   (~2 MB)
    bf16*  AO    = (bf16*)(ws + 28334080);         // 4096x1024 bf16   (8 MB) -> end ~35 MB

    prep_fused<<<4608, 256, 0, stream>>>(x, Wq, Wk, Wv, Wo, xb, WtQKV, WtO);

    gemm_bt<true, true><<<1536, 128, 0, stream>>>(
        xb, WtQKV, bq, bk, bv, QKV, Vt, 4096, 1536, 1024, 24, 8);

    attn_kernel<<<dim3(64, 16), 256, 0, stream>>>(QKV, Vt, AO);

    gemm_bt<false, false><<<1024, 128, 0, stream>>>(
        AO, WtO, bo, nullptr, nullptr, out, nullptr, 4096, 1024, 1024, 16, 8);
}

// Round 14
// 173.730 us; speedup vs baseline: 1.0648x; 1.0074x over previous
//
#include <hip/hip_runtime.h>

typedef __bf16 bf16;
typedef __bf16 bf16x4 __attribute__((ext_vector_type(4)));
typedef __bf16 bf16x8 __attribute__((ext_vector_type(8)));
typedef float f32x4 __attribute__((ext_vector_type(4)));
typedef float f32x16 __attribute__((ext_vector_type(16)));

#define T_LEN   4096
#define D_MODEL 1024
#define QKV_LD  1536
#define VT_LD   4128   // 4096 + 32 pad: last tile's PV chunk over-reads into pad (x0 P)
#define WINDOW  256

// async global->LDS, 16 B per lane; data lands at readfirstlane(l) + lane*16
__device__ __forceinline__ void gload_lds16(const bf16* g, bf16* l) {
    __builtin_amdgcn_global_load_lds((const __attribute__((address_space(1))) void*)g,
                                     (__attribute__((address_space(3))) void*)l, 16, 0, 0);
}

// ---------------- fused prep: x->bf16, Wq|Wk|Wv transpose, Wo transpose -----
// grid sections: [0,2048) cvt, [2048,3584) wqkv, [3584,4608) wo

__global__ __launch_bounds__(256) void prep_fused(
    const float* __restrict__ x,
    const float* __restrict__ Wq, const float* __restrict__ Wk,
    const float* __restrict__ Wv, const float* __restrict__ Wo,
    bf16* __restrict__ xb, bf16* __restrict__ WtQKV, bf16* __restrict__ WtO)
{
    __shared__ float t[32][33];
    const int blk = blockIdx.x;
    if (blk < 2048) {                       // ---- x (f32) -> xb (bf16)
        int i = (blk * 256 + threadIdx.x) * 8;
        float4 a = *(const float4*)(x + i);
        float4 b = *(const float4*)(x + i + 4);
        bf16x8 o;
        o[0] = (bf16)a.x; o[1] = (bf16)a.y; o[2] = (bf16)a.z; o[3] = (bf16)a.w;
        o[4] = (bf16)b.x; o[5] = (bf16)b.y; o[6] = (bf16)b.z; o[7] = (bf16)b.w;
        *(bf16x8*)(xb + i) = o;
        return;
    }
    const float* W; bf16* Wt; int n0, k0, Ns, nofs;
    if (blk < 3584) {                       // ---- Wq|Wk|Wv -> WtQKV (1536x1024)
        int b = blk - 2048;
        n0 = (b % 48) * 32; k0 = (b / 48) * 32;
        if (n0 < 1024)      { W = Wq; Ns = 1024; nofs = 0; }
        else if (n0 < 1280) { W = Wk; Ns = 256;  nofs = 1024; }
        else                { W = Wv; Ns = 256;  nofs = 1280; }
        Wt = WtQKV;
    } else {                                // ---- Wo -> WtO (1024x1024)
        int b = blk - 3584;
        n0 = (b % 32) * 32; k0 = (b / 32) * 32;
        W = Wo; Ns = 1024; nofs = 0; Wt = WtO;
    }
    int tx = threadIdx.x & 31, ty = threadIdx.x >> 5;
#pragma unroll
    for (int it = 0; it < 4; ++it)
        t[ty + it * 8][tx] = W[(size_t)(k0 + ty + it * 8) * Ns + (n0 - nofs) + tx];
    __syncthreads();
#pragma unroll
    for (int it = 0; it < 4; ++it)
        Wt[(size_t)(n0 + ty + it * 8) * 1024 + k0 + tx] = (bf16)t[tx][ty + it * 8];
}

// ---------------- GEMM: C(MxN) = A(MxK)*Bt(NxK)^T + bias ----------------
// R9 frame (128 thr / 2 waves, block tile 64x64, 3-buffer LDS pipeline,
// raw s_barrier + partial vmcnt, XCD swizzle, 24 KB LDS -> 6 blocks/CU)
// with the MFMA shape swapped to 32x32x16: wave tile 32(m)x64(n) = 2 tiles
// of 32x32, acc 2x16 f32. Per K-iter: 4 MFMA (8 cyc each) + 6 ds_read_b128
// (was 8 MFMA x 4.85 cyc + 6 reads) -> ~18% less MFMA issue time, longer
// uninterrupted MFMA runs. Staging/LDS layout byte-identical to R9.
// 32x32 layouts (HW-verified m74/m101): A/B frag [m|n=lane&31][k=(lane>>5)*8+j];
// C/D col=lane&31, row=(reg&3)+8*(reg>>2)+4*(lane>>5).
// QKV_BIAS: col-blocks n0>=1280 are V -> written transposed to Vt.

template <bool OUT_BF16, bool QKV_BIAS>
__global__ __launch_bounds__(128) void gemm_bt(
    const bf16* __restrict__ A, const bf16* __restrict__ Bt,
    const float* __restrict__ b0, const float* __restrict__ b1,
    const float* __restrict__ b2, void* __restrict__ Cv, bf16* __restrict__ Vt,
    int M, int N, int K, int nbx, int bands_per_xcd)
{
    __shared__ bf16 As[3][64 * 32];
    __shared__ bf16 Bs[3][64 * 32];
    const int blk = blockIdx.x;
    const int xcd = blk & 7;
    const int s   = blk >> 3;
    const int m0 = (xcd * bands_per_xcd + s / nbx) * 64;
    const int n0 = (s % nbx) * 64;
    const int tid  = threadIdx.x;
    const int w    = tid >> 6, lane = tid & 63;
    const int l32  = lane & 31, khalf = lane >> 5;

    f32x16 acc[2] = {};   // two 32x32 tiles: n-halves of the wave's 32x64

    // staging: seg id in [0,256) per operand tile; 16 B per seg (R9 exact)
    const int segA0 = w * 128 + lane;          // inst t=0
    const int segA1 = w * 128 + 64 + lane;     // inst t=1
    const bf16* gA0 = A  + (size_t)(m0 + (segA0 >> 2)) * K + (segA0 & 3) * 8;
    const bf16* gA1 = A  + (size_t)(m0 + (segA1 >> 2)) * K + (segA1 & 3) * 8;
    const bf16* gB0 = Bt + (size_t)(n0 + (segA0 >> 2)) * K + (segA0 & 3) * 8;
    const bf16* gB1 = Bt + (size_t)(n0 + (segA1 >> 2)) * K + (segA1 & 3) * 8;
    const int dA0 = segA0 * 8, dA1 = segA1 * 8;   // element offsets in LDS tile

    int bc = 0, bn = 1, bo = 2;   // current / next / overwrite buffer ids

    // prologue: stage kt=0 -> buf0, kt=1 -> buf1 (8 wave-loads in flight)
    gload_lds16(gA0,      &As[0][0] + dA0);
    gload_lds16(gA1,      &As[0][0] + dA1);
    gload_lds16(gB0,      &Bs[0][0] + dA0);
    gload_lds16(gB1,      &Bs[0][0] + dA1);
    gload_lds16(gA0 + 32, &As[1][0] + dA0);
    gload_lds16(gA1 + 32, &As[1][0] + dA1);
    gload_lds16(gB0 + 32, &Bs[1][0] + dA0);
    gload_lds16(gB1 + 32, &Bs[1][0] + dA1);

    // fragment LDS offsets: A rows w*32+l32; B rows jt*32+l32; k-chunk c*16+khalf*8
    const int ra = (w * 32 + l32) * 32 + khalf * 8;        // + c*16
    const int rb0 = (l32) * 32 + khalf * 8;                // n-tile 0
    const int rb1 = (32 + l32) * 32 + khalf * 8;           // n-tile 1

    const int nk = K >> 5;
    for (int kt = 0; kt < nk; ++kt) {
        if (kt + 1 < nk) asm volatile("s_waitcnt vmcnt(4)" ::: "memory");
        else             asm volatile("s_waitcnt vmcnt(0)" ::: "memory");
        asm volatile("s_barrier" ::: "memory");
        if (kt + 2 < nk) {
            gload_lds16(gA0 + (kt + 2) * 32, &As[bo][0] + dA0);
            gload_lds16(gA1 + (kt + 2) * 32, &As[bo][0] + dA1);
            gload_lds16(gB0 + (kt + 2) * 32, &Bs[bo][0] + dA0);
            gload_lds16(gB1 + (kt + 2) * 32, &Bs[bo][0] + dA1);
        }
        const bf16* Ac = &As[bc][0];
        const bf16* Bc = &Bs[bc][0];
        bf16x8 af0 = *(const bf16x8*)(Ac + ra);
        bf16x8 af1 = *(const bf16x8*)(Ac + ra + 16);
        bf16x8 b00 = *(const bf16x8*)(Bc + rb0);
        bf16x8 b01 = *(const bf16x8*)(Bc + rb0 + 16);
        bf16x8 b10 = *(const bf16x8*)(Bc + rb1);
        bf16x8 b11 = *(const bf16x8*)(Bc + rb1 + 16);
        acc[0] = __builtin_amdgcn_mfma_f32_32x32x16_bf16(af0, b00, acc[0], 0, 0, 0);
        acc[1] = __builtin_amdgcn_mfma_f32_32x32x16_bf16(af0, b10, acc[1], 0, 0, 0);
        acc[0] = __builtin_amdgcn_mfma_f32_32x32x16_bf16(af1, b01, acc[0], 0, 0, 0);
        acc[1] = __builtin_amdgcn_mfma_f32_32x32x16_bf16(af1, b11, acc[1], 0, 0, 0);
        int t = bc; bc = bn; bn = bo; bo = t;
    }

    // epilogue: 32x32 C/D layout: col = lane&31, row = (r&3)+8*(r>>2)+4*khalf
    const bool vtile = QKV_BIAS && (n0 >= 1280);
#pragma unroll
    for (int jt = 0; jt < 2; ++jt) {
        const int col = n0 + jt * 32 + l32;
        const float bb = QKV_BIAS
            ? (col < 1024 ? b0[col] : (col < 1280 ? b1[col - 1024] : b2[col - 1280]))
            : b0[col];
        if (vtile) {
#pragma unroll
            for (int g = 0; g < 4; ++g) {
                bf16x4 pv;
#pragma unroll
                for (int s2 = 0; s2 < 4; ++s2) pv[s2] = (bf16)(acc[jt][g * 4 + s2] + bb);
                *(bf16x4*)&Vt[(size_t)(col - 1280) * VT_LD + m0 + w * 32 + g * 8 + khalf * 4] = pv;
            }
        } else {
#pragma unroll
            for (int g = 0; g < 4; ++g) {
                const int row0 = m0 + w * 32 + g * 8 + khalf * 4;
#pragma unroll
                for (int s2 = 0; s2 < 4; ++s2) {
                    const float v = acc[jt][g * 4 + s2] + bb;
                    if (OUT_BF16) ((bf16*)Cv)[(size_t)(row0 + s2) * N + col] = (bf16)v;
                    else          ((float*)Cv)[(size_t)(row0 + s2) * N + col] = v;
                }
            }
        }
    }
}

// ---------------- attention: 4 waves/block, 1 wave per (16-query tile, head) --
// Window <= 272 keys -> 17 S tiles of 16, PV over 9 K-chunks of 32.

__global__ __launch_bounds__(256) void attn_kernel(
    const bf16* __restrict__ QKV, const bf16* __restrict__ Vt, bf16* __restrict__ Oa)
{
    __shared__ bf16 Ps[4][16][296];   // per-wave P tile; 592 B rows: 2-way alias only
    const int wave = threadIdx.x >> 6;
    const int lane = threadIdx.x & 63;
    const int q0 = (blockIdx.x * 4 + wave) * 16;
    const int h  = blockIdx.y;
    const int kh = h >> 2;                     // GQA: head h -> kv head h/4
    const int quad = lane >> 4, l16 = lane & 15;
    const float slope = exp2f(-0.5f * (float)(h + 1));   // NH=16 ALiBi slopes
    const int lo = (q0 >= 256) ? (q0 - 256) : 0;          // window start

    // Q A-fragments (k-chunks 0 and 32 of HD=64)
    const bf16* qp = QKV + (size_t)(q0 + l16) * QKV_LD + h * 64 + quad * 8;
    bf16x8 qf0 = *(const bf16x8*)qp;
    bf16x8 qf1 = *(const bf16x8*)(qp + 32);

    // S = Q K^T : 17 tiles of 16 keys, fully unrolled so s[] stays in VGPRs
    f32x4 s[17];
#pragma unroll
    for (int t = 0; t < 17; ++t) {
        const bf16* kp = QKV + (size_t)(lo + t * 16 + l16) * QKV_LD + D_MODEL + kh * 64 + quad * 8;
        bf16x8 kf0 = *(const bf16x8*)kp;
        bf16x8 kf1 = *(const bf16x8*)(kp + 32);
        f32x4 a = {};
        a = __builtin_amdgcn_mfma_f32_16x16x32_bf16(qf0, kf0, a, 0, 0, 0);
        a = __builtin_amdgcn_mfma_f32_16x16x32_bf16(qf1, kf1, a, 0, 0, 0);
        s[t] = a;
    }

    // masked ALiBi softmax; lane holds rows quad*4+r at col l16 of each tile
    float rinv[4];
#pragma unroll
    for (int r = 0; r < 4; ++r) {
        const int row = q0 + quad * 4 + r;
        float mx = -1e30f;
#pragma unroll
        for (int t = 0; t < 17; ++t) {
            const int key = lo + t * 16 + l16;
            float v = s[t][r] * 0.125f - slope * (float)(row - key);
            const bool ok = (key <= row) && (key > row - WINDOW);
            v = ok ? v : -1e30f;
            s[t][r] = v;
            mx = fmaxf(mx, v);
        }
#pragma unroll
        for (int d = 1; d < 16; d <<= 1) mx = fmaxf(mx, __shfl_xor(mx, d));
        float sum = 0.f;
#pragma unroll
        for (int t = 0; t < 17; ++t) {
            float p = __expf(s[t][r] - mx);
            s[t][r] = p;
            sum += p;
        }
#pragma unroll
        for (int d = 1; d < 16; d <<= 1) sum += __shfl_xor(sum, d);
        rinv[r] = 1.f / sum;
    }

    // zero pad cols [272,288) (PV reads 288 cols)
    {
        int idx = lane;
#pragma unroll
        for (int it = 0; it < 4; ++it) {
            Ps[wave][(idx >> 4) & 15][272 + (idx & 15)] = (bf16)0.f;
            idx += 64;
        }
    }
    // P: C-layout regs -> LDS -> A-layout frags
#pragma unroll
    for (int t = 0; t < 17; ++t)
#pragma unroll
        for (int r = 0; r < 4; ++r)
            Ps[wave][quad * 4 + r][t * 16 + l16] = (bf16)(s[t][r] * rinv[r]);
    __syncthreads();

    // O = P V : V B-frags straight from global Vt (contiguous along keys)
    f32x4 o[4] = {};
#pragma unroll
    for (int c = 0; c < 9; ++c) {
        bf16x8 pf = *(const bf16x8*)&Ps[wave][l16][c * 32 + quad * 8];
#pragma unroll
        for (int j = 0; j < 4; ++j) {
            const bf16* vp = Vt + (size_t)(kh * 64 + j * 16 + l16) * VT_LD + lo + c * 32 + quad * 8;
            bf16x8 vf = *(const bf16x8*)vp;
            o[j] = __builtin_amdgcn_mfma_f32_16x16x32_bf16(pf, vf, o[j], 0, 0, 0);
        }
    }

#pragma unroll
    for (int j = 0; j < 4; ++j)
#pragma unroll
        for (int r = 0; r < 4; ++r)
            Oa[(size_t)(q0 + quad * 4 + r) * D_MODEL + h * 64 + j * 16 + l16] = (bf16)o[j][r];
}

// ---------------- launch ----------------

extern "C" void kernel_launch(void* const* d_in, const int* in_sizes, int n_in,
                              void* d_out, int out_size, void* d_ws, size_t ws_size,
                              hipStream_t stream) {
    const float* x  = (const float*)d_in[0];
    const float* Wq = (const float*)d_in[1];
    const float* bq = (const float*)d_in[2];
    const float* Wk = (const float*)d_in[3];
    const float* bk = (const float*)d_in[4];
    const float* Wv = (const float*)d_in[5];
    const float* bv = (const float*)d_in[6];
    const float* Wo = (const float*)d_in[7];
    const float* bo = (const float*)d_in[8];
    float* out = (float*)d_out;

    char* ws = (char*)d_ws;
    bf16*  xb    = (bf16*)(ws);                    // 4096x1024 bf16   (8 MB)
    bf16*  WtQKV = (bf16*)(ws + 8388608);          // 1536x1024 bf16   (3 MB)
    bf16*  WtO   = (bf16*)(ws + 11534336);         // 1024x1024 bf16   (2 MB)
    bf16*  QKV   = (bf16*)(ws + 13637632);         // 4096x1536 bf16   (12 MB; V region unused)
    bf16*  Vt    = (bf16*)(ws + 26220544);         // 256xVT_LD bf16   (~2 MB)
    bf16*  AO    = (bf16*)(ws + 28334080);         // 4096x1024 bf16   (8 MB) -> end ~35 MB

    prep_fused<<<4608, 256, 0, stream>>>(x, Wq, Wk, Wv, Wo, xb, WtQKV, WtO);

    gemm_bt<true, true><<<1536, 128, 0, stream>>>(
        xb, WtQKV, bq, bk, bv, QKV, Vt, 4096, 1536, 1024, 24, 8);

    attn_kernel<<<dim3(64, 16), 256, 0, stream>>>(QKV, Vt, AO);

    gemm_bt<false, false><<<1024, 128, 0, stream>>>(
        AO, WtO, bo, nullptr, nullptr, out, nullptr, 4096, 1024, 1024, 16, 8);
}